// Round 1
// baseline (3040.338 us; speedup 1.0000x reference)
//
#include <hip/hip_runtime.h>
#include <cstdint>
#include <cstddef>

// ---------------------------------------------------------------------------
// DeepCNNLSTM_EncoderMOE on MI355X (gfx950)
// Round 1: full correct pipeline. f16 MFMA convs (top-2 expert skip),
// fused GN+GELU passes, persistent per-batch LSTM with dot2 f16.
// ---------------------------------------------------------------------------

#define DEVI __device__ __forceinline__

typedef _Float16 f16;
typedef _Float16 f16x8 __attribute__((ext_vector_type(8)));
typedef _Float16 f16x2 __attribute__((ext_vector_type(2)));
typedef _Float16 f16x4v __attribute__((ext_vector_type(4)));
typedef float    f32x4 __attribute__((ext_vector_type(4)));
typedef unsigned int u32;

static constexpr int B   = 64;
static constexpr int T   = 512;
static constexpr int NC  = 10;

// ---- workspace layout (bytes) ----
constexpr size_t SZ_WS1 = (size_t)5*64*32*2;        // shared L1 weights [5][64][32] f16
constexpr size_t SZ_WS2 = (size_t)5*128*64*2;
constexpr size_t SZ_WS3 = (size_t)5*256*128*2;
constexpr size_t SZ_WE1 = 8*SZ_WS1;
constexpr size_t SZ_WE2 = 8*SZ_WS2;
constexpr size_t SZ_WE3 = 8*SZ_WS3;
constexpr size_t SZ_WR  = (size_t)5*128*32*2;
constexpr size_t SZ_WIH = (size_t)1024*256*2;       // [1024][256] f16
constexpr size_t SZ_WHH = (size_t)128*1024*4;       // [128][1024] u32 (f16 pairs)
constexpr size_t SZ_ACT0 = (size_t)B*T*32*2;
constexpr size_t SZ_A1   = (size_t)B*T*64*2;
constexpr size_t SZ_A2   = (size_t)B*T*128*2;
constexpr size_t SZ_RACT = (size_t)B*T*128*2;
constexpr size_t SZ_CONV = (size_t)B*T*256*4;
constexpr size_t SZ_HMIX = (size_t)B*T*256*4;
constexpr size_t SZ_AMIX = (size_t)B*T*256*2;
constexpr size_t SZ_U    = (size_t)B*T*1024*2;
constexpr size_t SZ_STAT = (size_t)B*8*2*4;
constexpr size_t SZ_RH   = (size_t)B*128*4;
constexpr size_t SZ_WSEL = (size_t)B*8*4;
constexpr size_t SZ_HT   = (size_t)B*256*4;

constexpr size_t OFF_WS1  = 0;
constexpr size_t OFF_WS2  = OFF_WS1 + SZ_WS1;
constexpr size_t OFF_WS3  = OFF_WS2 + SZ_WS2;
constexpr size_t OFF_WE1  = OFF_WS3 + SZ_WS3;
constexpr size_t OFF_WE2  = OFF_WE1 + SZ_WE1;
constexpr size_t OFF_WE3  = OFF_WE2 + SZ_WE2;
constexpr size_t OFF_WR   = OFF_WE3 + SZ_WE3;
constexpr size_t OFF_WIH  = OFF_WR  + SZ_WR;
constexpr size_t OFF_WHH  = OFF_WIH + SZ_WIH;
constexpr size_t OFF_ACT0 = OFF_WHH + SZ_WHH;
constexpr size_t OFF_A1   = OFF_ACT0 + SZ_ACT0;
constexpr size_t OFF_A2   = OFF_A1 + SZ_A1;
constexpr size_t OFF_RACT = OFF_A2 + SZ_A2;
constexpr size_t OFF_CONV = OFF_RACT + SZ_RACT;
constexpr size_t OFF_HMIX = OFF_CONV + SZ_CONV;
constexpr size_t OFF_AMIX = OFF_HMIX + SZ_HMIX;
constexpr size_t OFF_U    = OFF_AMIX + SZ_AMIX;
constexpr size_t OFF_STAT = OFF_U + SZ_U;
constexpr size_t OFF_RH   = OFF_STAT + SZ_STAT;
constexpr size_t OFF_WSEL = OFF_RH + SZ_RH;
constexpr size_t OFF_HT   = OFF_WSEL + SZ_WSEL;
constexpr size_t WS_TOTAL = OFF_HT + SZ_HT;         // ~179.1 MB

DEVI float geluf(float x){ return 0.5f*x*(1.f + erff(x*0.70710678118654752f)); }
DEVI float fsig(float x){ return 1.f/(1.f + __expf(-x)); }
DEVI float ftanh(float x){ float e = __expf(-2.f*x); return (1.f-e)/(1.f+e); }

// ---------------------------------------------------------------------------
// Weight prep: transpose all conv weights to [k][co][ci] f16 (ci padded to 32
// for 16-ch inputs), W_ih -> [1024][256] f16, W_hh -> [128][1024] packed f16x2.
// ---------------------------------------------------------------------------
DEVI void fill_convw(f16* dst, const float* src, int COUT, int CI, int CIP, int idx){
  int s  = idx / (COUT*CIP);
  int r  = idx - s*(COUT*CIP);
  int co = r / CIP;
  int ci = r - co*CIP;
  float v = (ci < CI) ? src[((size_t)co*CI + ci)*5 + s] : 0.f;
  dst[idx] = (f16)v;
}

__global__ __launch_bounds__(256) void k_prep_w(
    const float* eW1, const float* eW2, const float* eW3,
    const float* sW1, const float* sW2, const float* sW3, const float* rW,
    const float* Wih, const float* Whh, char* ws)
{
  int i = blockIdx.x*256 + threadIdx.x;
  if (i < 10240){ fill_convw((f16*)(ws+OFF_WS1), sW1, 64, 16, 32, i); return; } i -= 10240;
  if (i < 40960){ fill_convw((f16*)(ws+OFF_WS2), sW2, 128, 64, 64, i); return; } i -= 40960;
  if (i < 163840){ fill_convw((f16*)(ws+OFF_WS3), sW3, 256, 128, 128, i); return; } i -= 163840;
  if (i < 81920){ int e=i/10240, r=i-e*10240;
    fill_convw((f16*)(ws+OFF_WE1)+ (size_t)e*10240, eW1 + (size_t)e*64*16*5, 64, 16, 32, r); return; } i -= 81920;
  if (i < 327680){ int e=i/40960, r=i-e*40960;
    fill_convw((f16*)(ws+OFF_WE2)+ (size_t)e*40960, eW2 + (size_t)e*128*64*5, 128, 64, 64, r); return; } i -= 327680;
  if (i < 1310720){ int e=i/163840, r=i-e*163840;
    fill_convw((f16*)(ws+OFF_WE3)+ (size_t)e*163840, eW3 + (size_t)e*256*128*5, 256, 128, 128, r); return; } i -= 1310720;
  if (i < 20480){ fill_convw((f16*)(ws+OFF_WR), rW, 128, 16, 32, i); return; } i -= 20480;
  if (i < 262144){ // W_ih (256,1024) -> [j][k]
    int j = i >> 8, k = i & 255;
    ((f16*)(ws+OFF_WIH))[i] = (f16)Wih[(size_t)k*1024 + j]; return; } i -= 262144;
  if (i < 131072){ // W_hh (256,1024) -> packed pairs [i2][j]
    int i2 = i >> 10, j = i & 1023;
    f16 a = (f16)Whh[(size_t)(2*i2)*1024 + j];
    f16 b = (f16)Whh[(size_t)(2*i2+1)*1024 + j];
    u32 u = (u32)__builtin_bit_cast(unsigned short, a)
          | ((u32)__builtin_bit_cast(unsigned short, b) << 16);
    ((u32*)(ws+OFF_WHH))[i] = u; return; }
}

__global__ __launch_bounds__(256) void k_prep_x(const float* __restrict__ x, char* ws){
  int idx = blockIdx.x*256 + threadIdx.x;
  if (idx >= B*T*32) return;
  int b = idx/(T*32); int r = idx - b*(T*32); int t = r >> 5; int c = r & 31;
  f16 v = (c < 16) ? (f16)x[((size_t)b*16 + c)*T + t] : (f16)0.f;
  ((f16*)(ws+OFF_ACT0))[idx] = v;
}

// ---------------------------------------------------------------------------
// Conv / GEMM via MFMA f16. act: (B,T,CIN) f16. wt: [NSHIFT][COUT][CIN] f16.
// out: (B,T,COUT) f32 (or f16 when OUTF16). Optional bias; optional per-(b,e)
// skip via bsel (w_hard).
// ---------------------------------------------------------------------------
template<int CIN, int NSHIFT, bool OUTF16>
__global__ __launch_bounds__(256) void k_conv(
    const f16* __restrict__ act, const f16* __restrict__ wt,
    void* __restrict__ outp, const float* __restrict__ bias,
    const float* __restrict__ bsel, int esel, int COUT)
{
  int mt = blockIdx.x;
  int b  = mt >> 3;            // T/64 == 8 tiles per batch row
  int t0 = (mt & 7) << 6;
  if (bsel && bsel[b*8 + esel] == 0.f) return;
  int n0   = blockIdx.y << 6;
  int tid  = threadIdx.x;
  int wave = tid >> 6, lane = tid & 63;
  int lr = lane & 15, lk = lane >> 4;

  f32x4 acc[4];
  #pragma unroll
  for (int nf=0; nf<4; ++nf) acc[nf] = f32x4{0.f,0.f,0.f,0.f};

  const f16* abase = act + (size_t)b*T*CIN;
  int trow = t0 + wave*16 + lr;

  #pragma unroll
  for (int s=0; s<NSHIFT; ++s){
    int tg = (NSHIFT==5) ? (trow + s - 2) : trow;
    bool valid = (unsigned)tg < (unsigned)T;
    const f16* arow = abase + (long)tg*CIN + lk*8;
    #pragma unroll
    for (int c0=0; c0<CIN; c0+=32){
      f16x8 af = {(f16)0,(f16)0,(f16)0,(f16)0,(f16)0,(f16)0,(f16)0,(f16)0};
      if (valid) af = *(const f16x8*)(arow + c0);
      #pragma unroll
      for (int nf=0; nf<4; ++nf){
        int col = n0 + nf*16 + lr;
        f16x8 bf = *(const f16x8*)(wt + ((size_t)s*COUT + col)*CIN + c0 + lk*8);
        acc[nf] = __builtin_amdgcn_mfma_f32_16x16x32_f16(af, bf, acc[nf], 0, 0, 0);
      }
    }
  }

  #pragma unroll
  for (int nf=0; nf<4; ++nf){
    int col = n0 + nf*16 + lr;
    float bv = bias ? bias[col] : 0.f;
    #pragma unroll
    for (int r=0; r<4; ++r){
      int trw = t0 + wave*16 + lk*4 + r;
      size_t o = ((size_t)b*T + trw)*COUT + col;
      float v = acc[nf][r] + bv;
      if (OUTF16) ((f16*)outp)[o] = (f16)v;
      else        ((float*)outp)[o] = v;
    }
  }
}

// ---------------------------------------------------------------------------
// GroupNorm stats per (b,g) over (CPG x T) of fp32 (B,T,C)
// ---------------------------------------------------------------------------
template<int CPG>
__global__ __launch_bounds__(256) void k_gnstats(
    const float* __restrict__ xin, float* __restrict__ stats,
    const float* __restrict__ bsel, int esel)
{
  constexpr int C = CPG*8;
  int b = blockIdx.x >> 3, g = blockIdx.x & 7;
  if (bsel && bsel[b*8 + esel] == 0.f) return;
  const float* base = xin + (size_t)b*T*C + g*CPG;
  float sum = 0.f, ss = 0.f;
  constexpr int N = CPG*T;
  for (int i = threadIdx.x; i < N; i += 256){
    int t = i / CPG, c = i % CPG;
    float v = base[(size_t)t*C + c];
    sum += v; ss += v*v;
  }
  #pragma unroll
  for (int off=32; off; off>>=1){ sum += __shfl_down(sum, off); ss += __shfl_down(ss, off); }
  __shared__ float rs[8];
  int wave = threadIdx.x >> 6, lane = threadIdx.x & 63;
  if (lane == 0){ rs[wave] = sum; rs[4+wave] = ss; }
  __syncthreads();
  if (threadIdx.x == 0){
    float S = rs[0]+rs[1]+rs[2]+rs[3], Q = rs[4]+rs[5]+rs[6]+rs[7];
    float m = S/(float)N;
    float var = Q/(float)N - m*m;
    stats[(b*8+g)*2]   = m;
    stats[(b*8+g)*2+1] = rsqrtf(var + 1e-5f);
  }
}

// ---------------------------------------------------------------------------
// GN normalize + GELU. MODE 0: write f16 act. MODE 1: hmix = v (shared).
// MODE 2: hmix += w*v (expert, skipped if w==0).
// ---------------------------------------------------------------------------
template<int CPG, int MODE>
__global__ __launch_bounds__(256) void k_gnapply(
    const float* __restrict__ xin, const float* __restrict__ stats,
    const float* __restrict__ gamma, const float* __restrict__ beta,
    void* __restrict__ outp, const float* __restrict__ bsel, int esel)
{
  constexpr int C = CPG*8;
  size_t base = ((size_t)blockIdx.x*256 + threadIdx.x)*4;
  if (base >= (size_t)B*T*C) return;
  int b = (int)(base / ((size_t)T*C));
  float w = 1.f;
  if (bsel){ w = bsel[b*8 + esel]; if (w == 0.f) return; }
  int c0 = (int)(base % C);
  int g  = c0 / CPG;
  float m  = stats[(b*8+g)*2];
  float rs = stats[(b*8+g)*2+1];
  f32x4 xv = *(const f32x4*)(xin + base);
  float o[4];
  #pragma unroll
  for (int k=0; k<4; ++k){
    float xn = (xv[k]-m)*rs*gamma[c0+k] + beta[c0+k];
    o[k] = geluf(xn);
  }
  if constexpr (MODE == 0){
    f16x4v h4 = {(f16)o[0],(f16)o[1],(f16)o[2],(f16)o[3]};
    *(f16x4v*)((f16*)outp + base) = h4;
  } else if constexpr (MODE == 1){
    f32x4 r = {o[0],o[1],o[2],o[3]};
    *(f32x4*)((float*)outp + base) = r;
  } else {
    float* hp = (float*)outp + base;
    f32x4 old = *(const f32x4*)hp;
    f32x4 r = {old[0]+w*o[0], old[1]+w*o[1], old[2]+w*o[2], old[3]+w*o[3]};
    *(f32x4*)hp = r;
  }
}

__global__ __launch_bounds__(256) void k_h2f16(const float* __restrict__ src,
                                               f16* __restrict__ dst, int n4){
  int idx = blockIdx.x*256 + threadIdx.x;
  if (idx >= n4) return;
  f32x4 v = *(const f32x4*)(src + (size_t)idx*4);
  f16x4v h = {(f16)v[0],(f16)v[1],(f16)v[2],(f16)v[3]};
  *(f16x4v*)(dst + (size_t)idx*4) = h;
}

// ---------------------------------------------------------------------------
// Router: GAP over T, then MLP + LN + gate softmax + top-2 renormalize
// ---------------------------------------------------------------------------
__global__ __launch_bounds__(512) void k_gap(const f16* __restrict__ ract,
                                             float* __restrict__ rh){
  int b = blockIdx.x;
  int c = threadIdx.x & 127, st = threadIdx.x >> 7;   // 4 t-strips
  const f16* p = ract + (size_t)b*T*128 + c;
  float s = 0.f;
  for (int t = st; t < T; t += 4) s += (float)p[(size_t)t*128];
  __shared__ float acc[512];
  acc[threadIdx.x] = s;
  __syncthreads();
  if (st == 0) rh[b*128 + c] = (acc[c] + acc[128+c] + acc[256+c] + acc[384+c]) * (1.f/(float)T);
}

__global__ __launch_bounds__(128) void k_router(
    const float* __restrict__ rh,
    const float* __restrict__ m1W, const float* __restrict__ m1b,
    const float* __restrict__ lng, const float* __restrict__ lnb,
    const float* __restrict__ m2W, const float* __restrict__ m2b,
    const float* __restrict__ gW,  const float* __restrict__ gb,
    float* __restrict__ wsel)
{
  int b = blockIdx.x, j = threadIdx.x;
  __shared__ float sbuf[128];
  __shared__ float red[4];
  __shared__ float z2[64];
  sbuf[j] = rh[b*128 + j];
  __syncthreads();
  float acc = m1b[j];
  for (int k=0; k<128; ++k) acc += sbuf[k]*m1W[k*128 + j];
  float s1 = acc, s2 = acc*acc;
  #pragma unroll
  for (int off=32; off; off>>=1){ s1 += __shfl_down(s1, off); s2 += __shfl_down(s2, off); }
  int wid = j >> 6, lane = j & 63;
  if (lane == 0){ red[wid] = s1; red[2+wid] = s2; }
  __syncthreads();
  float S = red[0]+red[1], Q = red[2]+red[3];
  float m = S*(1.f/128.f), var = Q*(1.f/128.f) - m*m;
  float xn = (acc - m)*rsqrtf(var + 1e-5f)*lng[j] + lnb[j];
  float ge = geluf(xn);
  __syncthreads();
  sbuf[j] = ge;
  __syncthreads();
  if (j < 64){
    float a = m2b[j];
    for (int k=0; k<128; ++k) a += sbuf[k]*m2W[k*64 + j];
    z2[j] = a;
  }
  __syncthreads();
  if (j == 0){
    float lg[8];
    for (int e=0; e<8; ++e){
      float a = gb[e];
      for (int k=0; k<64; ++k) a += z2[k]*gW[k*8 + e];
      lg[e] = a;
    }
    float mx = lg[0];
    for (int e=1; e<8; ++e) mx = fmaxf(mx, lg[e]);
    float p[8], sum = 0.f;
    for (int e=0; e<8; ++e){ p[e] = __expf(lg[e]-mx); sum += p[e]; }
    float inv = 1.f/sum;
    for (int e=0; e<8; ++e) p[e] *= inv;
    int i1 = 0;
    for (int e=1; e<8; ++e) if (p[e] > p[i1]) i1 = e;
    int i2 = -1;
    for (int e=0; e<8; ++e){ if (e==i1) continue; if (i2 < 0 || p[e] > p[i2]) i2 = e; }
    float s = p[i1] + p[i2] + 1e-9f;
    for (int e=0; e<8; ++e) wsel[b*8+e] = (e==i1 || e==i2) ? p[e]/s : 0.f;
  }
}

// ---------------------------------------------------------------------------
// Persistent LSTM: 1 WG per batch elem, thread j owns gate column j.
// W_hh column held in 128 packed-f16 VGPRs; h broadcast via LDS; dot2 f16.
// ---------------------------------------------------------------------------
DEVI float dot2acc(u32 wu, u32 hu, float acc){
#if __has_builtin(__builtin_amdgcn_fdot2)
  return __builtin_amdgcn_fdot2(__builtin_bit_cast(f16x2, wu),
                                __builtin_bit_cast(f16x2, hu), acc, false);
#else
  f16x2 a = __builtin_bit_cast(f16x2, wu), b = __builtin_bit_cast(f16x2, hu);
  return acc + (float)a.x*(float)b.x + (float)a.y*(float)b.y;
#endif
}

__global__ __launch_bounds__(1024) void k_lstm(const u32* __restrict__ whh,
    const f16* __restrict__ U, float* __restrict__ hTout)
{
  int b = blockIdx.x, j = threadIdx.x;
  u32 w[128];
  #pragma unroll
  for (int i=0; i<128; ++i) w[i] = whh[(size_t)i*1024 + j];

  __shared__ __align__(16) u32 hp[128];
  __shared__ float gbuf[1024];
  if (j < 128) hp[j] = 0u;
  float c0=0.f, c1=0.f, h0=0.f, h1=0.f;
  const f16* Ub = U + (size_t)b*T*1024 + j;
  float unext = (float)Ub[0];
  __syncthreads();

  for (int t=0; t<T; ++t){
    float acc = unext;
    if (t+1 < T) unext = (float)Ub[(size_t)(t+1)*1024];
    #pragma unroll
    for (int i=0; i<128; i+=4){
      uint4 q = *(const uint4*)(hp + i);
      acc = dot2acc(w[i+0], q.x, acc);
      acc = dot2acc(w[i+1], q.y, acc);
      acc = dot2acc(w[i+2], q.z, acc);
      acc = dot2acc(w[i+3], q.w, acc);
    }
    gbuf[j] = acc;
    __syncthreads();
    if (j < 128){
      float i0 = gbuf[2*j],     i1 = gbuf[2*j+1];
      float f0 = gbuf[256+2*j], f1 = gbuf[256+2*j+1];
      float g0 = gbuf[512+2*j], g1 = gbuf[512+2*j+1];
      float o0 = gbuf[768+2*j], o1 = gbuf[768+2*j+1];
      c0 = fsig(f0)*c0 + fsig(i0)*ftanh(g0);
      c1 = fsig(f1)*c1 + fsig(i1)*ftanh(g1);
      h0 = fsig(o0)*ftanh(c0);
      h1 = fsig(o1)*ftanh(c1);
      f16 ha = (f16)h0, hb = (f16)h1;
      hp[j] = (u32)__builtin_bit_cast(unsigned short, ha)
            | ((u32)__builtin_bit_cast(unsigned short, hb) << 16);
    }
    __syncthreads();
  }
  if (j < 128){
    hTout[b*256 + 2*j]     = h0;
    hTout[b*256 + 2*j + 1] = h1;
  }
}

__global__ __launch_bounds__(256) void k_head(const float* __restrict__ hT,
    const float* __restrict__ Wc, const float* __restrict__ bc,
    float* __restrict__ out)
{
  int b = blockIdx.x, j = threadIdx.x;
  __shared__ float hs[256];
  hs[j] = hT[b*256 + j];
  __syncthreads();
  if (j < NC){
    float a = bc[j];
    for (int k=0; k<256; ++k) a += hs[k]*Wc[k*NC + j];
    out[b*NC + j] = a;
  }
}

// ---------------------------------------------------------------------------
extern "C" void kernel_launch(void* const* d_in, const int* in_sizes, int n_in,
                              void* d_out, int out_size, void* d_ws, size_t ws_size,
                              hipStream_t stream)
{
  if (ws_size < WS_TOTAL) return;  // deterministic guard (needs ~179.2 MB)

  const float* x    = (const float*)d_in[0];
  const float* eW1  = (const float*)d_in[1];
  const float* eg1  = (const float*)d_in[2];
  const float* eb1  = (const float*)d_in[3];
  const float* eW2  = (const float*)d_in[4];
  const float* eg2  = (const float*)d_in[5];
  const float* eb2  = (const float*)d_in[6];
  const float* eW3  = (const float*)d_in[7];
  const float* eg3  = (const float*)d_in[8];
  const float* eb3  = (const float*)d_in[9];
  const float* sW1  = (const float*)d_in[10];
  const float* sg1  = (const float*)d_in[11];
  const float* sb1  = (const float*)d_in[12];
  const float* sW2  = (const float*)d_in[13];
  const float* sg2  = (const float*)d_in[14];
  const float* sb2  = (const float*)d_in[15];
  const float* sW3  = (const float*)d_in[16];
  const float* sg3  = (const float*)d_in[17];
  const float* sb3  = (const float*)d_in[18];
  const float* rW   = (const float*)d_in[19];
  const float* rg   = (const float*)d_in[20];
  const float* rb   = (const float*)d_in[21];
  const float* rm1W = (const float*)d_in[22];
  const float* rm1b = (const float*)d_in[23];
  const float* rlng = (const float*)d_in[24];
  const float* rlnb = (const float*)d_in[25];
  const float* rm2W = (const float*)d_in[26];
  const float* rm2b = (const float*)d_in[27];
  const float* gW   = (const float*)d_in[28];
  const float* gb   = (const float*)d_in[29];
  const float* Wih  = (const float*)d_in[30];
  const float* Whh  = (const float*)d_in[31];
  const float* blst = (const float*)d_in[32];
  const float* Wc   = (const float*)d_in[33];
  const float* bc   = (const float*)d_in[34];

  char* ws = (char*)d_ws;
  f16*  ws1   = (f16*)(ws + OFF_WS1);
  f16*  ws2   = (f16*)(ws + OFF_WS2);
  f16*  ws3   = (f16*)(ws + OFF_WS3);
  f16*  we1   = (f16*)(ws + OFF_WE1);
  f16*  we2   = (f16*)(ws + OFF_WE2);
  f16*  we3   = (f16*)(ws + OFF_WE3);
  f16*  wr    = (f16*)(ws + OFF_WR);
  f16*  wih   = (f16*)(ws + OFF_WIH);
  u32*  whh   = (u32*)(ws + OFF_WHH);
  f16*  act0  = (f16*)(ws + OFF_ACT0);
  f16*  a1    = (f16*)(ws + OFF_A1);
  f16*  a2    = (f16*)(ws + OFF_A2);
  f16*  ract  = (f16*)(ws + OFF_RACT);
  float* convb = (float*)(ws + OFF_CONV);
  float* hmix  = (float*)(ws + OFF_HMIX);
  f16*  amix  = (f16*)(ws + OFF_AMIX);
  f16*  Ubuf  = (f16*)(ws + OFF_U);
  float* stats = (float*)(ws + OFF_STAT);
  float* rh    = (float*)(ws + OFF_RH);
  float* wsel  = (float*)(ws + OFF_WSEL);
  float* hTb   = (float*)(ws + OFF_HT);

  // ---- prep ----
  k_prep_w<<<(2349056 + 255)/256, 256, 0, stream>>>(eW1,eW2,eW3,sW1,sW2,sW3,rW,Wih,Whh,ws);
  k_prep_x<<<(B*T*32 + 255)/256, 256, 0, stream>>>(x, ws);

  // ---- router ----
  k_conv<32,5,false><<<dim3(512,2), 256, 0, stream>>>(act0, wr, convb, nullptr, nullptr, 0, 128);
  k_gnstats<16><<<B*8, 256, 0, stream>>>(convb, stats, nullptr, 0);
  k_gnapply<16,0><<<(B*T*128)/1024, 256, 0, stream>>>(convb, stats, rg, rb, ract, nullptr, 0);
  k_gap<<<B, 512, 0, stream>>>(ract, rh);
  k_router<<<B, 128, 0, stream>>>(rh, rm1W, rm1b, rlng, rlnb, rm2W, rm2b, gW, gb, wsel);

  // ---- shared expert (always on) -> hmix = result ----
  k_conv<32,5,false><<<dim3(512,1), 256, 0, stream>>>(act0, ws1, convb, nullptr, nullptr, 0, 64);
  k_gnstats<8><<<B*8, 256, 0, stream>>>(convb, stats, nullptr, 0);
  k_gnapply<8,0><<<(B*T*64)/1024, 256, 0, stream>>>(convb, stats, sg1, sb1, a1, nullptr, 0);
  k_conv<64,5,false><<<dim3(512,2), 256, 0, stream>>>(a1, ws2, convb, nullptr, nullptr, 0, 128);
  k_gnstats<16><<<B*8, 256, 0, stream>>>(convb, stats, nullptr, 0);
  k_gnapply<16,0><<<(B*T*128)/1024, 256, 0, stream>>>(convb, stats, sg2, sb2, a2, nullptr, 0);
  k_conv<128,5,false><<<dim3(512,4), 256, 0, stream>>>(a2, ws3, convb, nullptr, nullptr, 0, 256);
  k_gnstats<32><<<B*8, 256, 0, stream>>>(convb, stats, nullptr, 0);
  k_gnapply<32,1><<<(B*T*256)/1024, 256, 0, stream>>>(convb, stats, sg3, sb3, hmix, nullptr, 0);

  // ---- experts (top-2 skip via wsel) -> hmix += w * result ----
  for (int e=0; e<8; ++e){
    k_conv<32,5,false><<<dim3(512,1), 256, 0, stream>>>(act0, we1 + (size_t)e*10240, convb, nullptr, wsel, e, 64);
    k_gnstats<8><<<B*8, 256, 0, stream>>>(convb, stats, wsel, e);
    k_gnapply<8,0><<<(B*T*64)/1024, 256, 0, stream>>>(convb, stats, eg1 + e*64, eb1 + e*64, a1, wsel, e);
    k_conv<64,5,false><<<dim3(512,2), 256, 0, stream>>>(a1, we2 + (size_t)e*40960, convb, nullptr, wsel, e, 128);
    k_gnstats<16><<<B*8, 256, 0, stream>>>(convb, stats, wsel, e);
    k_gnapply<16,0><<<(B*T*128)/1024, 256, 0, stream>>>(convb, stats, eg2 + e*128, eb2 + e*128, a2, wsel, e);
    k_conv<128,5,false><<<dim3(512,4), 256, 0, stream>>>(a2, we3 + (size_t)e*163840, convb, nullptr, wsel, e, 256);
    k_gnstats<32><<<B*8, 256, 0, stream>>>(convb, stats, wsel, e);
    k_gnapply<32,2><<<(B*T*256)/1024, 256, 0, stream>>>(convb, stats, eg3 + e*256, eb3 + e*256, hmix, wsel, e);
  }

  // ---- LSTM ----
  k_h2f16<<<(B*T*256/4 + 255)/256, 256, 0, stream>>>(hmix, amix, B*T*256/4);
  k_conv<256,1,true><<<dim3(512,16), 256, 0, stream>>>(amix, wih, Ubuf, blst, nullptr, 0, 1024);
  k_lstm<<<B, 1024, 0, stream>>>(whh, Ubuf, hTb);
  k_head<<<B, 256, 0, stream>>>(hTb, Wc, bc, (float*)d_out);
}

// Round 2
// 2295.109 us; speedup vs baseline: 1.3247x; 1.3247x over previous
//
#include <hip/hip_runtime.h>
#include <cstdint>
#include <cstddef>

// ---------------------------------------------------------------------------
// DeepCNNLSTM_EncoderMOE on MI355X (gfx950)
// Round 2: LSTM rebuilt (VGPR+LDS split W_hh cache, no spill), f16 GN chain.
// ---------------------------------------------------------------------------

#define DEVI __device__ __forceinline__

typedef _Float16 f16;
typedef _Float16 f16x8 __attribute__((ext_vector_type(8)));
typedef _Float16 f16x2 __attribute__((ext_vector_type(2)));
typedef _Float16 f16x4v __attribute__((ext_vector_type(4)));
typedef float    f32x4 __attribute__((ext_vector_type(4)));
typedef unsigned int u32;
typedef unsigned short u16;

static constexpr int B   = 64;
static constexpr int T   = 512;
static constexpr int NC  = 10;

// ---- workspace layout (bytes) ----
constexpr size_t SZ_WS1 = (size_t)5*64*32*2;        // shared L1 weights [5][64][32] f16
constexpr size_t SZ_WS2 = (size_t)5*128*64*2;
constexpr size_t SZ_WS3 = (size_t)5*256*128*2;
constexpr size_t SZ_WE1 = 8*SZ_WS1;
constexpr size_t SZ_WE2 = 8*SZ_WS2;
constexpr size_t SZ_WE3 = 8*SZ_WS3;
constexpr size_t SZ_WR  = (size_t)5*128*32*2;
constexpr size_t SZ_WIH = (size_t)1024*256*2;       // [1024][256] f16
constexpr size_t SZ_WHH = (size_t)128*1024*4;       // [pair][1024] u32 (f16 pairs)
constexpr size_t SZ_ACT0 = (size_t)B*T*32*2;
constexpr size_t SZ_A1   = (size_t)B*T*64*2;
constexpr size_t SZ_A2   = (size_t)B*T*128*2;
constexpr size_t SZ_RACT = (size_t)B*T*128*2;
constexpr size_t SZ_CONV = (size_t)B*T*256*2;       // f16 now
constexpr size_t SZ_HMIX = (size_t)B*T*256*4;
constexpr size_t SZ_AMIX = (size_t)B*T*256*2;
constexpr size_t SZ_U    = (size_t)B*T*1024*2;
constexpr size_t SZ_STAT = (size_t)B*8*2*4;
constexpr size_t SZ_RH   = (size_t)B*128*4;
constexpr size_t SZ_WSEL = (size_t)B*8*4;
constexpr size_t SZ_HT   = (size_t)B*256*4;

constexpr size_t OFF_WS1  = 0;
constexpr size_t OFF_WS2  = OFF_WS1 + SZ_WS1;
constexpr size_t OFF_WS3  = OFF_WS2 + SZ_WS2;
constexpr size_t OFF_WE1  = OFF_WS3 + SZ_WS3;
constexpr size_t OFF_WE2  = OFF_WE1 + SZ_WE1;
constexpr size_t OFF_WE3  = OFF_WE2 + SZ_WE2;
constexpr size_t OFF_WR   = OFF_WE3 + SZ_WE3;
constexpr size_t OFF_WIH  = OFF_WR  + SZ_WR;
constexpr size_t OFF_WHH  = OFF_WIH + SZ_WIH;
constexpr size_t OFF_ACT0 = OFF_WHH + SZ_WHH;
constexpr size_t OFF_A1   = OFF_ACT0 + SZ_ACT0;
constexpr size_t OFF_A2   = OFF_A1 + SZ_A1;
constexpr size_t OFF_RACT = OFF_A2 + SZ_A2;
constexpr size_t OFF_CONV = OFF_RACT + SZ_RACT;
constexpr size_t OFF_HMIX = OFF_CONV + SZ_CONV;
constexpr size_t OFF_AMIX = OFF_HMIX + SZ_HMIX;
constexpr size_t OFF_U    = OFF_AMIX + SZ_AMIX;
constexpr size_t OFF_STAT = OFF_U + SZ_U;
constexpr size_t OFF_RH   = OFF_STAT + SZ_STAT;
constexpr size_t OFF_WSEL = OFF_RH + SZ_RH;
constexpr size_t OFF_HT   = OFF_WSEL + SZ_WSEL;
constexpr size_t WS_TOTAL = OFF_HT + SZ_HT;

DEVI float geluf(float x){ return 0.5f*x*(1.f + erff(x*0.70710678118654752f)); }
DEVI float fsig(float x){ return 1.f/(1.f + __expf(-x)); }
DEVI float ftanh(float x){ float e = __expf(-2.f*x); return (1.f-e)/(1.f+e); }

// ---------------------------------------------------------------------------
// Weight prep
// ---------------------------------------------------------------------------
DEVI void fill_convw(f16* dst, const float* src, int COUT, int CI, int CIP, int idx){
  int s  = idx / (COUT*CIP);
  int r  = idx - s*(COUT*CIP);
  int co = r / CIP;
  int ci = r - co*CIP;
  float v = (ci < CI) ? src[((size_t)co*CI + ci)*5 + s] : 0.f;
  dst[idx] = (f16)v;
}

__global__ __launch_bounds__(256) void k_prep_w(
    const float* eW1, const float* eW2, const float* eW3,
    const float* sW1, const float* sW2, const float* sW3, const float* rW,
    const float* Wih, const float* Whh, char* ws)
{
  int i = blockIdx.x*256 + threadIdx.x;
  if (i < 10240){ fill_convw((f16*)(ws+OFF_WS1), sW1, 64, 16, 32, i); return; } i -= 10240;
  if (i < 40960){ fill_convw((f16*)(ws+OFF_WS2), sW2, 128, 64, 64, i); return; } i -= 40960;
  if (i < 163840){ fill_convw((f16*)(ws+OFF_WS3), sW3, 256, 128, 128, i); return; } i -= 163840;
  if (i < 81920){ int e=i/10240, r=i-e*10240;
    fill_convw((f16*)(ws+OFF_WE1)+ (size_t)e*10240, eW1 + (size_t)e*64*16*5, 64, 16, 32, r); return; } i -= 81920;
  if (i < 327680){ int e=i/40960, r=i-e*40960;
    fill_convw((f16*)(ws+OFF_WE2)+ (size_t)e*40960, eW2 + (size_t)e*128*64*5, 128, 64, 64, r); return; } i -= 327680;
  if (i < 1310720){ int e=i/163840, r=i-e*163840;
    fill_convw((f16*)(ws+OFF_WE3)+ (size_t)e*163840, eW3 + (size_t)e*163840, 256, 128, 128, r); return; } i -= 1310720;
  if (i < 20480){ fill_convw((f16*)(ws+OFF_WR), rW, 128, 16, 32, i); return; } i -= 20480;
  if (i < 262144){ // W_ih (256,1024) -> [j][k]
    int j = i >> 8, k = i & 255;
    ((f16*)(ws+OFF_WIH))[i] = (f16)Wih[(size_t)k*1024 + j]; return; } i -= 262144;
  if (i < 131072){ // W_hh (256,1024) -> packed row-pairs [pair][1024]
    int i2 = i >> 10, j = i & 1023;
    f16 a = (f16)Whh[(size_t)(2*i2)*1024 + j];
    f16 b = (f16)Whh[(size_t)(2*i2+1)*1024 + j];
    u32 u = (u32)__builtin_bit_cast(unsigned short, a)
          | ((u32)__builtin_bit_cast(unsigned short, b) << 16);
    ((u32*)(ws+OFF_WHH))[i] = u; return; }
}

__global__ __launch_bounds__(256) void k_prep_x(const float* __restrict__ x, char* ws){
  int idx = blockIdx.x*256 + threadIdx.x;
  if (idx >= B*T*32) return;
  int b = idx/(T*32); int r = idx - b*(T*32); int t = r >> 5; int c = r & 31;
  f16 v = (c < 16) ? (f16)x[((size_t)b*16 + c)*T + t] : (f16)0.f;
  ((f16*)(ws+OFF_ACT0))[idx] = v;
}

// ---------------------------------------------------------------------------
// Conv / GEMM via MFMA f16. act: (B,T,CIN) f16. wt: [NSHIFT][COUT][CIN] f16.
// out: (B,T,COUT) f16. Optional bias; optional per-(b,e) skip via bsel.
// ---------------------------------------------------------------------------
template<int CIN, int NSHIFT>
__global__ __launch_bounds__(256) void k_conv(
    const f16* __restrict__ act, const f16* __restrict__ wt,
    f16* __restrict__ outp, const float* __restrict__ bias,
    const float* __restrict__ bsel, int esel, int COUT)
{
  int mt = blockIdx.x;
  int b  = mt >> 3;
  int t0 = (mt & 7) << 6;
  if (bsel && bsel[b*8 + esel] == 0.f) return;
  int n0   = blockIdx.y << 6;
  int tid  = threadIdx.x;
  int wave = tid >> 6, lane = tid & 63;
  int lr = lane & 15, lk = lane >> 4;

  f32x4 acc[4];
  #pragma unroll
  for (int nf=0; nf<4; ++nf) acc[nf] = f32x4{0.f,0.f,0.f,0.f};

  const f16* abase = act + (size_t)b*T*CIN;
  int trow = t0 + wave*16 + lr;

  #pragma unroll
  for (int s=0; s<NSHIFT; ++s){
    int tg = (NSHIFT==5) ? (trow + s - 2) : trow;
    bool valid = (unsigned)tg < (unsigned)T;
    const f16* arow = abase + (long)tg*CIN + lk*8;
    #pragma unroll
    for (int c0=0; c0<CIN; c0+=32){
      f16x8 af = {(f16)0,(f16)0,(f16)0,(f16)0,(f16)0,(f16)0,(f16)0,(f16)0};
      if (valid) af = *(const f16x8*)(arow + c0);
      #pragma unroll
      for (int nf=0; nf<4; ++nf){
        int col = n0 + nf*16 + lr;
        f16x8 bf = *(const f16x8*)(wt + ((size_t)s*COUT + col)*CIN + c0 + lk*8);
        acc[nf] = __builtin_amdgcn_mfma_f32_16x16x32_f16(af, bf, acc[nf], 0, 0, 0);
      }
    }
  }

  #pragma unroll
  for (int nf=0; nf<4; ++nf){
    int col = n0 + nf*16 + lr;
    float bv = bias ? bias[col] : 0.f;
    #pragma unroll
    for (int r=0; r<4; ++r){
      int trw = t0 + wave*16 + lk*4 + r;
      size_t o = ((size_t)b*T + trw)*COUT + col;
      outp[o] = (f16)(acc[nf][r] + bv);
    }
  }
}

// ---------------------------------------------------------------------------
// GroupNorm stats per (b,g) over (CPG x T) of f16 (B,T,C)
// ---------------------------------------------------------------------------
template<int CPG>
__global__ __launch_bounds__(256) void k_gnstats(
    const f16* __restrict__ xin, float* __restrict__ stats,
    const float* __restrict__ bsel, int esel)
{
  constexpr int C = CPG*8;
  constexpr int V = CPG/8;   // f16x8 vectors per (t) in this group
  int b = blockIdx.x >> 3, g = blockIdx.x & 7;
  if (bsel && bsel[b*8 + esel] == 0.f) return;
  const f16* base = xin + (size_t)b*T*C + g*CPG;
  float sum = 0.f, ss = 0.f;
  for (int i = threadIdx.x; i < T*V; i += 256){
    int t = i / V, v = i - (i/V)*V;
    f16x8 xv = *(const f16x8*)(base + (size_t)t*C + v*8);
    #pragma unroll
    for (int k=0;k<8;++k){ float f = (float)xv[k]; sum += f; ss += f*f; }
  }
  #pragma unroll
  for (int off=32; off; off>>=1){ sum += __shfl_down(sum, off); ss += __shfl_down(ss, off); }
  __shared__ float rs[8];
  int wave = threadIdx.x >> 6, lane = threadIdx.x & 63;
  if (lane == 0){ rs[wave] = sum; rs[4+wave] = ss; }
  __syncthreads();
  if (threadIdx.x == 0){
    float S = rs[0]+rs[1]+rs[2]+rs[3], Q = rs[4]+rs[5]+rs[6]+rs[7];
    constexpr float N = (float)(CPG*T);
    float m = S/N;
    float var = Q/N - m*m;
    stats[(b*8+g)*2]   = m;
    stats[(b*8+g)*2+1] = rsqrtf(var + 1e-5f);
  }
}

// ---------------------------------------------------------------------------
// GN normalize + GELU (8 elems/thread). MODE 0: write f16 act.
// MODE 1: hmix = v (f32). MODE 2: hmix += w*v.
// ---------------------------------------------------------------------------
template<int CPG, int MODE>
__global__ __launch_bounds__(256) void k_gnapply(
    const f16* __restrict__ xin, const float* __restrict__ stats,
    const float* __restrict__ gamma, const float* __restrict__ beta,
    void* __restrict__ outp, const float* __restrict__ bsel, int esel)
{
  constexpr int C = CPG*8;
  size_t base = ((size_t)blockIdx.x*256 + threadIdx.x)*8;
  if (base >= (size_t)B*T*C) return;
  int b = (int)(base / ((size_t)T*C));
  float w = 1.f;
  if (bsel){ w = bsel[b*8 + esel]; if (w == 0.f) return; }
  int c0 = (int)(base % C);
  int g  = c0 / CPG;
  float m  = stats[(b*8+g)*2];
  float rs = stats[(b*8+g)*2+1];
  f16x8 xv = *(const f16x8*)(xin + base);
  float o[8];
  #pragma unroll
  for (int k=0; k<8; ++k){
    float xn = ((float)xv[k]-m)*rs*gamma[c0+k] + beta[c0+k];
    o[k] = geluf(xn);
  }
  if constexpr (MODE == 0){
    f16x8 h8;
    #pragma unroll
    for (int k=0;k<8;++k) h8[k] = (f16)o[k];
    *(f16x8*)((f16*)outp + base) = h8;
  } else if constexpr (MODE == 1){
    float* hp = (float*)outp + base;
    *(f32x4*)hp     = f32x4{o[0],o[1],o[2],o[3]};
    *(f32x4*)(hp+4) = f32x4{o[4],o[5],o[6],o[7]};
  } else {
    float* hp = (float*)outp + base;
    f32x4 a = *(const f32x4*)hp, c = *(const f32x4*)(hp+4);
    *(f32x4*)hp     = f32x4{a[0]+w*o[0], a[1]+w*o[1], a[2]+w*o[2], a[3]+w*o[3]};
    *(f32x4*)(hp+4) = f32x4{c[0]+w*o[4], c[1]+w*o[5], c[2]+w*o[6], c[3]+w*o[7]};
  }
}

__global__ __launch_bounds__(256) void k_h2f16(const float* __restrict__ src,
                                               f16* __restrict__ dst, int n4){
  int idx = blockIdx.x*256 + threadIdx.x;
  if (idx >= n4) return;
  f32x4 v = *(const f32x4*)(src + (size_t)idx*4);
  f16x4v h = {(f16)v[0],(f16)v[1],(f16)v[2],(f16)v[3]};
  *(f16x4v*)(dst + (size_t)idx*4) = h;
}

// ---------------------------------------------------------------------------
// Router
// ---------------------------------------------------------------------------
__global__ __launch_bounds__(512) void k_gap(const f16* __restrict__ ract,
                                             float* __restrict__ rh){
  int b = blockIdx.x;
  int c = threadIdx.x & 127, st = threadIdx.x >> 7;
  const f16* p = ract + (size_t)b*T*128 + c;
  float s = 0.f;
  for (int t = st; t < T; t += 4) s += (float)p[(size_t)t*128];
  __shared__ float acc[512];
  acc[threadIdx.x] = s;
  __syncthreads();
  if (st == 0) rh[b*128 + c] = (acc[c] + acc[128+c] + acc[256+c] + acc[384+c]) * (1.f/(float)T);
}

__global__ __launch_bounds__(128) void k_router(
    const float* __restrict__ rh,
    const float* __restrict__ m1W, const float* __restrict__ m1b,
    const float* __restrict__ lng, const float* __restrict__ lnb,
    const float* __restrict__ m2W, const float* __restrict__ m2b,
    const float* __restrict__ gW,  const float* __restrict__ gb,
    float* __restrict__ wsel)
{
  int b = blockIdx.x, j = threadIdx.x;
  __shared__ float sbuf[128];
  __shared__ float red[4];
  __shared__ float z2[64];
  sbuf[j] = rh[b*128 + j];
  __syncthreads();
  float acc = m1b[j];
  for (int k=0; k<128; ++k) acc += sbuf[k]*m1W[k*128 + j];
  float s1 = acc, s2 = acc*acc;
  #pragma unroll
  for (int off=32; off; off>>=1){ s1 += __shfl_down(s1, off); s2 += __shfl_down(s2, off); }
  int wid = j >> 6, lane = j & 63;
  if (lane == 0){ red[wid] = s1; red[2+wid] = s2; }
  __syncthreads();
  float S = red[0]+red[1], Q = red[2]+red[3];
  float m = S*(1.f/128.f), var = Q*(1.f/128.f) - m*m;
  float xn = (acc - m)*rsqrtf(var + 1e-5f)*lng[j] + lnb[j];
  float ge = geluf(xn);
  __syncthreads();
  sbuf[j] = ge;
  __syncthreads();
  if (j < 64){
    float a = m2b[j];
    for (int k=0; k<128; ++k) a += sbuf[k]*m2W[k*64 + j];
    z2[j] = a;
  }
  __syncthreads();
  if (j == 0){
    float lg[8];
    for (int e=0; e<8; ++e){
      float a = gb[e];
      for (int k=0; k<64; ++k) a += z2[k]*gW[k*8 + e];
      lg[e] = a;
    }
    float mx = lg[0];
    for (int e=1; e<8; ++e) mx = fmaxf(mx, lg[e]);
    float p[8], sum = 0.f;
    for (int e=0; e<8; ++e){ p[e] = __expf(lg[e]-mx); sum += p[e]; }
    float inv = 1.f/sum;
    for (int e=0; e<8; ++e) p[e] *= inv;
    int i1 = 0;
    for (int e=1; e<8; ++e) if (p[e] > p[i1]) i1 = e;
    int i2 = -1;
    for (int e=0; e<8; ++e){ if (e==i1) continue; if (i2 < 0 || p[e] > p[i2]) i2 = e; }
    float s = p[i1] + p[i2] + 1e-9f;
    for (int e=0; e<8; ++e) wsel[b*8+e] = (e==i1 || e==i2) ? p[e]/s : 0.f;
  }
}

// ---------------------------------------------------------------------------
// Persistent LSTM v2: 1 WG (512 threads) per batch elem. Thread j owns gate
// columns j and j+512. W_hh column cache: pairs [0,104) in VGPRs (208 regs),
// pairs [104,128) in LDS ([col][26] padded stride -> 2-way bank alias, free).
// h broadcast via LDS (ushort[256]); gates -> LDS; 256 threads update h.
// ---------------------------------------------------------------------------
constexpr int PV = 104;      // row-pairs cached in VGPRs per column
constexpr int PL = 24;       // row-pairs in LDS per column
constexpr int LSTR = 26;     // padded u32 stride per column in LDS

DEVI float dot2acc(u32 wu, u32 hu, float acc){
#if __has_builtin(__builtin_amdgcn_fdot2)
  return __builtin_amdgcn_fdot2(__builtin_bit_cast(f16x2, wu),
                                __builtin_bit_cast(f16x2, hu), acc, false);
#else
  f16x2 a = __builtin_bit_cast(f16x2, wu), b = __builtin_bit_cast(f16x2, hu);
  return acc + (float)a.x*(float)b.x + (float)a.y*(float)b.y;
#endif
}

__global__ __launch_bounds__(512, 2) void k_lstm(const u32* __restrict__ whh,
    const f16* __restrict__ U, float* __restrict__ hTout)
{
  int b = blockIdx.x, j = threadIdx.x;
  int j2 = j + 512;

  __shared__ u32 wl[1024*LSTR];               // 104 KB
  __shared__ __align__(16) u16 hp16[256];     // packed f16 h
  __shared__ float gbuf[1024];

  u32 w0[PV], w1[PV];
  #pragma unroll
  for (int i=0; i<PV; ++i) w0[i] = whh[(size_t)i*1024 + j];
  #pragma unroll
  for (int i=0; i<PV; ++i) w1[i] = whh[(size_t)i*1024 + j2];
  #pragma unroll
  for (int p=0; p<PL; ++p){
    wl[j*LSTR + p]  = whh[(size_t)(PV+p)*1024 + j];
    wl[j2*LSTR + p] = whh[(size_t)(PV+p)*1024 + j2];
  }
  if (j < 256) hp16[j] = 0;

  float cst = 0.f, hst = 0.f;     // cell/hidden state for dim j (j<256)
  const f16* Ub = U + (size_t)b*T*1024;
  float u0n = (float)Ub[j];
  float u1n = (float)Ub[j2];
  __syncthreads();

  const u32* hp = (const u32*)hp16;   // 128 packed pairs
  for (int t=0; t<T; ++t){
    float a0a = u0n, a1a = u1n, a0b = 0.f, a1b = 0.f;
    if (t+1 < T){
      u0n = (float)Ub[(size_t)(t+1)*1024 + j];
      u1n = (float)Ub[(size_t)(t+1)*1024 + j2];
    }
    // VGPR-resident part: pairs [0,104), 4 independent acc chains
    #pragma unroll
    for (int i=0; i<PV; i+=8){
      uint4 q0 = *(const uint4*)(hp + i);
      uint4 q1 = *(const uint4*)(hp + i + 4);
      a0a = dot2acc(w0[i+0], q0.x, a0a); a0a = dot2acc(w0[i+1], q0.y, a0a);
      a0a = dot2acc(w0[i+2], q0.z, a0a); a0a = dot2acc(w0[i+3], q0.w, a0a);
      a1a = dot2acc(w1[i+0], q0.x, a1a); a1a = dot2acc(w1[i+1], q0.y, a1a);
      a1a = dot2acc(w1[i+2], q0.z, a1a); a1a = dot2acc(w1[i+3], q0.w, a1a);
      a0b = dot2acc(w0[i+4], q1.x, a0b); a0b = dot2acc(w0[i+5], q1.y, a0b);
      a0b = dot2acc(w0[i+6], q1.z, a0b); a0b = dot2acc(w0[i+7], q1.w, a0b);
      a1b = dot2acc(w1[i+4], q1.x, a1b); a1b = dot2acc(w1[i+5], q1.y, a1b);
      a1b = dot2acc(w1[i+6], q1.z, a1b); a1b = dot2acc(w1[i+7], q1.w, a1b);
    }
    // LDS-resident part: pairs [104,128)
    const u32* wp0 = wl + j*LSTR;
    const u32* wp1 = wl + j2*LSTR;
    #pragma unroll
    for (int p=0; p<PL; p+=2){
      uint2 hq = *(const uint2*)(hp + PV + p);
      uint2 wa = *(const uint2*)(wp0 + p);
      uint2 wb = *(const uint2*)(wp1 + p);
      a0a = dot2acc(wa.x, hq.x, a0a); a0b = dot2acc(wa.y, hq.y, a0b);
      a1a = dot2acc(wb.x, hq.x, a1a); a1b = dot2acc(wb.y, hq.y, a1b);
    }
    gbuf[j]  = a0a + a0b;
    gbuf[j2] = a1a + a1b;
    __syncthreads();
    if (j < 256){
      float gi = gbuf[j];
      float gf = gbuf[256 + j];
      float gg = gbuf[512 + j];
      float go = gbuf[768 + j];
      cst = fsig(gf)*cst + fsig(gi)*ftanh(gg);
      hst = fsig(go)*ftanh(cst);
      hp16[j] = __builtin_bit_cast(u16, (f16)hst);
    }
    __syncthreads();
  }
  if (j < 256) hTout[b*256 + j] = hst;
}

__global__ __launch_bounds__(256) void k_head(const float* __restrict__ hT,
    const float* __restrict__ Wc, const float* __restrict__ bc,
    float* __restrict__ out)
{
  int b = blockIdx.x, j = threadIdx.x;
  __shared__ float hs[256];
  hs[j] = hT[b*256 + j];
  __syncthreads();
  if (j < NC){
    float a = bc[j];
    for (int k=0; k<256; ++k) a += hs[k]*Wc[k*NC + j];
    out[b*NC + j] = a;
  }
}

// ---------------------------------------------------------------------------
extern "C" void kernel_launch(void* const* d_in, const int* in_sizes, int n_in,
                              void* d_out, int out_size, void* d_ws, size_t ws_size,
                              hipStream_t stream)
{
  if (ws_size < WS_TOTAL) return;

  const float* x    = (const float*)d_in[0];
  const float* eW1  = (const float*)d_in[1];
  const float* eg1  = (const float*)d_in[2];
  const float* eb1  = (const float*)d_in[3];
  const float* eW2  = (const float*)d_in[4];
  const float* eg2  = (const float*)d_in[5];
  const float* eb2  = (const float*)d_in[6];
  const float* eW3  = (const float*)d_in[7];
  const float* eg3  = (const float*)d_in[8];
  const float* eb3  = (const float*)d_in[9];
  const float* sW1  = (const float*)d_in[10];
  const float* sg1  = (const float*)d_in[11];
  const float* sb1  = (const float*)d_in[12];
  const float* sW2  = (const float*)d_in[13];
  const float* sg2  = (const float*)d_in[14];
  const float* sb2  = (const float*)d_in[15];
  const float* sW3  = (const float*)d_in[16];
  const float* sg3  = (const float*)d_in[17];
  const float* sb3  = (const float*)d_in[18];
  const float* rW   = (const float*)d_in[19];
  const float* rg   = (const float*)d_in[20];
  const float* rb   = (const float*)d_in[21];
  const float* rm1W = (const float*)d_in[22];
  const float* rm1b = (const float*)d_in[23];
  const float* rlng = (const float*)d_in[24];
  const float* rlnb = (const float*)d_in[25];
  const float* rm2W = (const float*)d_in[26];
  const float* rm2b = (const float*)d_in[27];
  const float* gW   = (const float*)d_in[28];
  const float* gb   = (const float*)d_in[29];
  const float* Wih  = (const float*)d_in[30];
  const float* Whh  = (const float*)d_in[31];
  const float* blst = (const float*)d_in[32];
  const float* Wc   = (const float*)d_in[33];
  const float* bc   = (const float*)d_in[34];

  char* ws = (char*)d_ws;
  f16*  ws1   = (f16*)(ws + OFF_WS1);
  f16*  ws2   = (f16*)(ws + OFF_WS2);
  f16*  ws3   = (f16*)(ws + OFF_WS3);
  f16*  we1   = (f16*)(ws + OFF_WE1);
  f16*  we2   = (f16*)(ws + OFF_WE2);
  f16*  we3   = (f16*)(ws + OFF_WE3);
  f16*  wr    = (f16*)(ws + OFF_WR);
  f16*  wih   = (f16*)(ws + OFF_WIH);
  u32*  whh   = (u32*)(ws + OFF_WHH);
  f16*  act0  = (f16*)(ws + OFF_ACT0);
  f16*  a1    = (f16*)(ws + OFF_A1);
  f16*  a2    = (f16*)(ws + OFF_A2);
  f16*  ract  = (f16*)(ws + OFF_RACT);
  f16*  convb = (f16*)(ws + OFF_CONV);
  float* hmix  = (float*)(ws + OFF_HMIX);
  f16*  amix  = (f16*)(ws + OFF_AMIX);
  f16*  Ubuf  = (f16*)(ws + OFF_U);
  float* stats = (float*)(ws + OFF_STAT);
  float* rh    = (float*)(ws + OFF_RH);
  float* wsel  = (float*)(ws + OFF_WSEL);
  float* hTb   = (float*)(ws + OFF_HT);

  // ---- prep ----
  k_prep_w<<<(2349056 + 255)/256, 256, 0, stream>>>(eW1,eW2,eW3,sW1,sW2,sW3,rW,Wih,Whh,ws);
  k_prep_x<<<(B*T*32 + 255)/256, 256, 0, stream>>>(x, ws);

  // ---- router ----
  k_conv<32,5><<<dim3(512,2), 256, 0, stream>>>(act0, wr, convb, nullptr, nullptr, 0, 128);
  k_gnstats<16><<<B*8, 256, 0, stream>>>(convb, stats, nullptr, 0);
  k_gnapply<16,0><<<(B*T*128)/2048, 256, 0, stream>>>(convb, stats, rg, rb, ract, nullptr, 0);
  k_gap<<<B, 512, 0, stream>>>(ract, rh);
  k_router<<<B, 128, 0, stream>>>(rh, rm1W, rm1b, rlng, rlnb, rm2W, rm2b, gW, gb, wsel);

  // ---- shared expert ----
  k_conv<32,5><<<dim3(512,1), 256, 0, stream>>>(act0, ws1, convb, nullptr, nullptr, 0, 64);
  k_gnstats<8><<<B*8, 256, 0, stream>>>(convb, stats, nullptr, 0);
  k_gnapply<8,0><<<(B*T*64)/2048, 256, 0, stream>>>(convb, stats, sg1, sb1, a1, nullptr, 0);
  k_conv<64,5><<<dim3(512,2), 256, 0, stream>>>(a1, ws2, convb, nullptr, nullptr, 0, 128);
  k_gnstats<16><<<B*8, 256, 0, stream>>>(convb, stats, nullptr, 0);
  k_gnapply<16,0><<<(B*T*128)/2048, 256, 0, stream>>>(convb, stats, sg2, sb2, a2, nullptr, 0);
  k_conv<128,5><<<dim3(512,4), 256, 0, stream>>>(a2, ws3, convb, nullptr, nullptr, 0, 256);
  k_gnstats<32><<<B*8, 256, 0, stream>>>(convb, stats, nullptr, 0);
  k_gnapply<32,1><<<(B*T*256)/2048, 256, 0, stream>>>(convb, stats, sg3, sb3, hmix, nullptr, 0);

  // ---- experts (top-2 skip) ----
  for (int e=0; e<8; ++e){
    k_conv<32,5><<<dim3(512,1), 256, 0, stream>>>(act0, we1 + (size_t)e*10240, convb, nullptr, wsel, e, 64);
    k_gnstats<8><<<B*8, 256, 0, stream>>>(convb, stats, wsel, e);
    k_gnapply<8,0><<<(B*T*64)/2048, 256, 0, stream>>>(convb, stats, eg1 + e*64, eb1 + e*64, a1, wsel, e);
    k_conv<64,5><<<dim3(512,2), 256, 0, stream>>>(a1, we2 + (size_t)e*40960, convb, nullptr, wsel, e, 128);
    k_gnstats<16><<<B*8, 256, 0, stream>>>(convb, stats, wsel, e);
    k_gnapply<16,0><<<(B*T*128)/2048, 256, 0, stream>>>(convb, stats, eg2 + e*128, eb2 + e*128, a2, wsel, e);
    k_conv<128,5><<<dim3(512,4), 256, 0, stream>>>(a2, we3 + (size_t)e*163840, convb, nullptr, wsel, e, 256);
    k_gnstats<32><<<B*8, 256, 0, stream>>>(convb, stats, wsel, e);
    k_gnapply<32,2><<<(B*T*256)/2048, 256, 0, stream>>>(convb, stats, eg3 + e*256, eb3 + e*256, hmix, wsel, e);
  }

  // ---- LSTM ----
  k_h2f16<<<(B*T*256/4 + 255)/256, 256, 0, stream>>>(hmix, amix, B*T*256/4);
  k_conv<256,1><<<dim3(512,16), 256, 0, stream>>>(amix, wih, Ubuf, blst, nullptr, 0, 1024);
  k_lstm<<<B, 512, 0, stream>>>(whh, Ubuf, hTb);
  k_head<<<B, 256, 0, stream>>>(hTb, Wc, bc, (float*)d_out);
}

// Round 3
// 2226.514 us; speedup vs baseline: 1.3655x; 1.0308x over previous
//
#include <hip/hip_runtime.h>
#include <cstdint>
#include <cstddef>

// ---------------------------------------------------------------------------
// DeepCNNLSTM_EncoderMOE on MI355X (gfx950)
// Round 3: LSTM launch_bounds(512,1) -> 1 block/CU -> 256 VGPR cap (second
// arg is min BLOCKS per CU: R1 1024thr->64regs, R2 (512,2)->128regs proved it).
// PV=96 pairs in VGPR (192 regs), PL=32 in LDS (stride 34 -> 2-way alias, free).
// ---------------------------------------------------------------------------

#define DEVI __device__ __forceinline__

typedef _Float16 f16;
typedef _Float16 f16x8 __attribute__((ext_vector_type(8)));
typedef _Float16 f16x2 __attribute__((ext_vector_type(2)));
typedef _Float16 f16x4v __attribute__((ext_vector_type(4)));
typedef float    f32x4 __attribute__((ext_vector_type(4)));
typedef unsigned int u32;
typedef unsigned short u16;

static constexpr int B   = 64;
static constexpr int T   = 512;
static constexpr int NC  = 10;

// ---- workspace layout (bytes) ----
constexpr size_t SZ_WS1 = (size_t)5*64*32*2;
constexpr size_t SZ_WS2 = (size_t)5*128*64*2;
constexpr size_t SZ_WS3 = (size_t)5*256*128*2;
constexpr size_t SZ_WE1 = 8*SZ_WS1;
constexpr size_t SZ_WE2 = 8*SZ_WS2;
constexpr size_t SZ_WE3 = 8*SZ_WS3;
constexpr size_t SZ_WR  = (size_t)5*128*32*2;
constexpr size_t SZ_WIH = (size_t)1024*256*2;
constexpr size_t SZ_WHH = (size_t)128*1024*4;
constexpr size_t SZ_ACT0 = (size_t)B*T*32*2;
constexpr size_t SZ_A1   = (size_t)B*T*64*2;
constexpr size_t SZ_A2   = (size_t)B*T*128*2;
constexpr size_t SZ_RACT = (size_t)B*T*128*2;
constexpr size_t SZ_CONV = (size_t)B*T*256*2;
constexpr size_t SZ_HMIX = (size_t)B*T*256*4;
constexpr size_t SZ_AMIX = (size_t)B*T*256*2;
constexpr size_t SZ_U    = (size_t)B*T*1024*2;
constexpr size_t SZ_STAT = (size_t)B*8*2*4;
constexpr size_t SZ_RH   = (size_t)B*128*4;
constexpr size_t SZ_WSEL = (size_t)B*8*4;
constexpr size_t SZ_HT   = (size_t)B*256*4;

constexpr size_t OFF_WS1  = 0;
constexpr size_t OFF_WS2  = OFF_WS1 + SZ_WS1;
constexpr size_t OFF_WS3  = OFF_WS2 + SZ_WS2;
constexpr size_t OFF_WE1  = OFF_WS3 + SZ_WS3;
constexpr size_t OFF_WE2  = OFF_WE1 + SZ_WE1;
constexpr size_t OFF_WE3  = OFF_WE2 + SZ_WE2;
constexpr size_t OFF_WR   = OFF_WE3 + SZ_WE3;
constexpr size_t OFF_WIH  = OFF_WR  + SZ_WR;
constexpr size_t OFF_WHH  = OFF_WIH + SZ_WIH;
constexpr size_t OFF_ACT0 = OFF_WHH + SZ_WHH;
constexpr size_t OFF_A1   = OFF_ACT0 + SZ_ACT0;
constexpr size_t OFF_A2   = OFF_A1 + SZ_A1;
constexpr size_t OFF_RACT = OFF_A2 + SZ_A2;
constexpr size_t OFF_CONV = OFF_RACT + SZ_RACT;
constexpr size_t OFF_HMIX = OFF_CONV + SZ_CONV;
constexpr size_t OFF_AMIX = OFF_HMIX + SZ_HMIX;
constexpr size_t OFF_U    = OFF_AMIX + SZ_AMIX;
constexpr size_t OFF_STAT = OFF_U + SZ_U;
constexpr size_t OFF_RH   = OFF_STAT + SZ_STAT;
constexpr size_t OFF_WSEL = OFF_RH + SZ_RH;
constexpr size_t OFF_HT   = OFF_WSEL + SZ_WSEL;
constexpr size_t WS_TOTAL = OFF_HT + SZ_HT;

DEVI float geluf(float x){ return 0.5f*x*(1.f + erff(x*0.70710678118654752f)); }
DEVI float fsig(float x){ return 1.f/(1.f + __expf(-x)); }
DEVI float ftanh(float x){ float e = __expf(-2.f*x); return (1.f-e)/(1.f+e); }

// ---------------------------------------------------------------------------
// Weight prep
// ---------------------------------------------------------------------------
DEVI void fill_convw(f16* dst, const float* src, int COUT, int CI, int CIP, int idx){
  int s  = idx / (COUT*CIP);
  int r  = idx - s*(COUT*CIP);
  int co = r / CIP;
  int ci = r - co*CIP;
  float v = (ci < CI) ? src[((size_t)co*CI + ci)*5 + s] : 0.f;
  dst[idx] = (f16)v;
}

__global__ __launch_bounds__(256) void k_prep_w(
    const float* eW1, const float* eW2, const float* eW3,
    const float* sW1, const float* sW2, const float* sW3, const float* rW,
    const float* Wih, const float* Whh, char* ws)
{
  int i = blockIdx.x*256 + threadIdx.x;
  if (i < 10240){ fill_convw((f16*)(ws+OFF_WS1), sW1, 64, 16, 32, i); return; } i -= 10240;
  if (i < 40960){ fill_convw((f16*)(ws+OFF_WS2), sW2, 128, 64, 64, i); return; } i -= 40960;
  if (i < 163840){ fill_convw((f16*)(ws+OFF_WS3), sW3, 256, 128, 128, i); return; } i -= 163840;
  if (i < 81920){ int e=i/10240, r=i-e*10240;
    fill_convw((f16*)(ws+OFF_WE1)+ (size_t)e*10240, eW1 + (size_t)e*64*16*5, 64, 16, 32, r); return; } i -= 81920;
  if (i < 327680){ int e=i/40960, r=i-e*40960;
    fill_convw((f16*)(ws+OFF_WE2)+ (size_t)e*40960, eW2 + (size_t)e*128*64*5, 128, 64, 64, r); return; } i -= 327680;
  if (i < 1310720){ int e=i/163840, r=i-e*163840;
    fill_convw((f16*)(ws+OFF_WE3)+ (size_t)e*163840, eW3 + (size_t)e*163840, 256, 128, 128, r); return; } i -= 1310720;
  if (i < 20480){ fill_convw((f16*)(ws+OFF_WR), rW, 128, 16, 32, i); return; } i -= 20480;
  if (i < 262144){ // W_ih (256,1024) -> [j][k]
    int j = i >> 8, k = i & 255;
    ((f16*)(ws+OFF_WIH))[i] = (f16)Wih[(size_t)k*1024 + j]; return; } i -= 262144;
  if (i < 131072){ // W_hh (256,1024) -> packed row-pairs [pair][1024]
    int i2 = i >> 10, j = i & 1023;
    f16 a = (f16)Whh[(size_t)(2*i2)*1024 + j];
    f16 b = (f16)Whh[(size_t)(2*i2+1)*1024 + j];
    u32 u = (u32)__builtin_bit_cast(unsigned short, a)
          | ((u32)__builtin_bit_cast(unsigned short, b) << 16);
    ((u32*)(ws+OFF_WHH))[i] = u; return; }
}

__global__ __launch_bounds__(256) void k_prep_x(const float* __restrict__ x, char* ws){
  int idx = blockIdx.x*256 + threadIdx.x;
  if (idx >= B*T*32) return;
  int b = idx/(T*32); int r = idx - b*(T*32); int t = r >> 5; int c = r & 31;
  f16 v = (c < 16) ? (f16)x[((size_t)b*16 + c)*T + t] : (f16)0.f;
  ((f16*)(ws+OFF_ACT0))[idx] = v;
}

// ---------------------------------------------------------------------------
// Conv / GEMM via MFMA f16
// ---------------------------------------------------------------------------
template<int CIN, int NSHIFT>
__global__ __launch_bounds__(256) void k_conv(
    const f16* __restrict__ act, const f16* __restrict__ wt,
    f16* __restrict__ outp, const float* __restrict__ bias,
    const float* __restrict__ bsel, int esel, int COUT)
{
  int mt = blockIdx.x;
  int b  = mt >> 3;
  int t0 = (mt & 7) << 6;
  if (bsel && bsel[b*8 + esel] == 0.f) return;
  int n0   = blockIdx.y << 6;
  int tid  = threadIdx.x;
  int wave = tid >> 6, lane = tid & 63;
  int lr = lane & 15, lk = lane >> 4;

  f32x4 acc[4];
  #pragma unroll
  for (int nf=0; nf<4; ++nf) acc[nf] = f32x4{0.f,0.f,0.f,0.f};

  const f16* abase = act + (size_t)b*T*CIN;
  int trow = t0 + wave*16 + lr;

  #pragma unroll
  for (int s=0; s<NSHIFT; ++s){
    int tg = (NSHIFT==5) ? (trow + s - 2) : trow;
    bool valid = (unsigned)tg < (unsigned)T;
    const f16* arow = abase + (long)tg*CIN + lk*8;
    #pragma unroll
    for (int c0=0; c0<CIN; c0+=32){
      f16x8 af = {(f16)0,(f16)0,(f16)0,(f16)0,(f16)0,(f16)0,(f16)0,(f16)0};
      if (valid) af = *(const f16x8*)(arow + c0);
      #pragma unroll
      for (int nf=0; nf<4; ++nf){
        int col = n0 + nf*16 + lr;
        f16x8 bf = *(const f16x8*)(wt + ((size_t)s*COUT + col)*CIN + c0 + lk*8);
        acc[nf] = __builtin_amdgcn_mfma_f32_16x16x32_f16(af, bf, acc[nf], 0, 0, 0);
      }
    }
  }

  #pragma unroll
  for (int nf=0; nf<4; ++nf){
    int col = n0 + nf*16 + lr;
    float bv = bias ? bias[col] : 0.f;
    #pragma unroll
    for (int r=0; r<4; ++r){
      int trw = t0 + wave*16 + lk*4 + r;
      size_t o = ((size_t)b*T + trw)*COUT + col;
      outp[o] = (f16)(acc[nf][r] + bv);
    }
  }
}

// ---------------------------------------------------------------------------
// GroupNorm stats per (b,g) over (CPG x T) of f16 (B,T,C)
// ---------------------------------------------------------------------------
template<int CPG>
__global__ __launch_bounds__(256) void k_gnstats(
    const f16* __restrict__ xin, float* __restrict__ stats,
    const float* __restrict__ bsel, int esel)
{
  constexpr int C = CPG*8;
  constexpr int V = CPG/8;
  int b = blockIdx.x >> 3, g = blockIdx.x & 7;
  if (bsel && bsel[b*8 + esel] == 0.f) return;
  const f16* base = xin + (size_t)b*T*C + g*CPG;
  float sum = 0.f, ss = 0.f;
  for (int i = threadIdx.x; i < T*V; i += 256){
    int t = i / V, v = i - (i/V)*V;
    f16x8 xv = *(const f16x8*)(base + (size_t)t*C + v*8);
    #pragma unroll
    for (int k=0;k<8;++k){ float f = (float)xv[k]; sum += f; ss += f*f; }
  }
  #pragma unroll
  for (int off=32; off; off>>=1){ sum += __shfl_down(sum, off); ss += __shfl_down(ss, off); }
  __shared__ float rs[8];
  int wave = threadIdx.x >> 6, lane = threadIdx.x & 63;
  if (lane == 0){ rs[wave] = sum; rs[4+wave] = ss; }
  __syncthreads();
  if (threadIdx.x == 0){
    float S = rs[0]+rs[1]+rs[2]+rs[3], Q = rs[4]+rs[5]+rs[6]+rs[7];
    constexpr float N = (float)(CPG*T);
    float m = S/N;
    float var = Q/N - m*m;
    stats[(b*8+g)*2]   = m;
    stats[(b*8+g)*2+1] = rsqrtf(var + 1e-5f);
  }
}

// ---------------------------------------------------------------------------
// GN normalize + GELU
// ---------------------------------------------------------------------------
template<int CPG, int MODE>
__global__ __launch_bounds__(256) void k_gnapply(
    const f16* __restrict__ xin, const float* __restrict__ stats,
    const float* __restrict__ gamma, const float* __restrict__ beta,
    void* __restrict__ outp, const float* __restrict__ bsel, int esel)
{
  constexpr int C = CPG*8;
  size_t base = ((size_t)blockIdx.x*256 + threadIdx.x)*8;
  if (base >= (size_t)B*T*C) return;
  int b = (int)(base / ((size_t)T*C));
  float w = 1.f;
  if (bsel){ w = bsel[b*8 + esel]; if (w == 0.f) return; }
  int c0 = (int)(base % C);
  int g  = c0 / CPG;
  float m  = stats[(b*8+g)*2];
  float rs = stats[(b*8+g)*2+1];
  f16x8 xv = *(const f16x8*)(xin + base);
  float o[8];
  #pragma unroll
  for (int k=0; k<8; ++k){
    float xn = ((float)xv[k]-m)*rs*gamma[c0+k] + beta[c0+k];
    o[k] = geluf(xn);
  }
  if constexpr (MODE == 0){
    f16x8 h8;
    #pragma unroll
    for (int k=0;k<8;++k) h8[k] = (f16)o[k];
    *(f16x8*)((f16*)outp + base) = h8;
  } else if constexpr (MODE == 1){
    float* hp = (float*)outp + base;
    *(f32x4*)hp     = f32x4{o[0],o[1],o[2],o[3]};
    *(f32x4*)(hp+4) = f32x4{o[4],o[5],o[6],o[7]};
  } else {
    float* hp = (float*)outp + base;
    f32x4 a = *(const f32x4*)hp, c = *(const f32x4*)(hp+4);
    *(f32x4*)hp     = f32x4{a[0]+w*o[0], a[1]+w*o[1], a[2]+w*o[2], a[3]+w*o[3]};
    *(f32x4*)(hp+4) = f32x4{c[0]+w*o[4], c[1]+w*o[5], c[2]+w*o[6], c[3]+w*o[7]};
  }
}

__global__ __launch_bounds__(256) void k_h2f16(const float* __restrict__ src,
                                               f16* __restrict__ dst, int n4){
  int idx = blockIdx.x*256 + threadIdx.x;
  if (idx >= n4) return;
  f32x4 v = *(const f32x4*)(src + (size_t)idx*4);
  f16x4v h = {(f16)v[0],(f16)v[1],(f16)v[2],(f16)v[3]};
  *(f16x4v*)(dst + (size_t)idx*4) = h;
}

// ---------------------------------------------------------------------------
// Router
// ---------------------------------------------------------------------------
__global__ __launch_bounds__(512) void k_gap(const f16* __restrict__ ract,
                                             float* __restrict__ rh){
  int b = blockIdx.x;
  int c = threadIdx.x & 127, st = threadIdx.x >> 7;
  const f16* p = ract + (size_t)b*T*128 + c;
  float s = 0.f;
  for (int t = st; t < T; t += 4) s += (float)p[(size_t)t*128];
  __shared__ float acc[512];
  acc[threadIdx.x] = s;
  __syncthreads();
  if (st == 0) rh[b*128 + c] = (acc[c] + acc[128+c] + acc[256+c] + acc[384+c]) * (1.f/(float)T);
}

__global__ __launch_bounds__(128) void k_router(
    const float* __restrict__ rh,
    const float* __restrict__ m1W, const float* __restrict__ m1b,
    const float* __restrict__ lng, const float* __restrict__ lnb,
    const float* __restrict__ m2W, const float* __restrict__ m2b,
    const float* __restrict__ gW,  const float* __restrict__ gb,
    float* __restrict__ wsel)
{
  int b = blockIdx.x, j = threadIdx.x;
  __shared__ float sbuf[128];
  __shared__ float red[4];
  __shared__ float z2[64];
  sbuf[j] = rh[b*128 + j];
  __syncthreads();
  float acc = m1b[j];
  for (int k=0; k<128; ++k) acc += sbuf[k]*m1W[k*128 + j];
  float s1 = acc, s2 = acc*acc;
  #pragma unroll
  for (int off=32; off; off>>=1){ s1 += __shfl_down(s1, off); s2 += __shfl_down(s2, off); }
  int wid = j >> 6, lane = j & 63;
  if (lane == 0){ red[wid] = s1; red[2+wid] = s2; }
  __syncthreads();
  float S = red[0]+red[1], Q = red[2]+red[3];
  float m = S*(1.f/128.f), var = Q*(1.f/128.f) - m*m;
  float xn = (acc - m)*rsqrtf(var + 1e-5f)*lng[j] + lnb[j];
  float ge = geluf(xn);
  __syncthreads();
  sbuf[j] = ge;
  __syncthreads();
  if (j < 64){
    float a = m2b[j];
    for (int k=0; k<128; ++k) a += sbuf[k]*m2W[k*64 + j];
    z2[j] = a;
  }
  __syncthreads();
  if (j == 0){
    float lg[8];
    for (int e=0; e<8; ++e){
      float a = gb[e];
      for (int k=0; k<64; ++k) a += z2[k]*gW[k*8 + e];
      lg[e] = a;
    }
    float mx = lg[0];
    for (int e=1; e<8; ++e) mx = fmaxf(mx, lg[e]);
    float p[8], sum = 0.f;
    for (int e=0; e<8; ++e){ p[e] = __expf(lg[e]-mx); sum += p[e]; }
    float inv = 1.f/sum;
    for (int e=0; e<8; ++e) p[e] *= inv;
    int i1 = 0;
    for (int e=1; e<8; ++e) if (p[e] > p[i1]) i1 = e;
    int i2 = -1;
    for (int e=0; e<8; ++e){ if (e==i1) continue; if (i2 < 0 || p[e] > p[i2]) i2 = e; }
    float s = p[i1] + p[i2] + 1e-9f;
    for (int e=0; e<8; ++e) wsel[b*8+e] = (e==i1 || e==i2) ? p[e]/s : 0.f;
  }
}

// ---------------------------------------------------------------------------
// Persistent LSTM v3: 1 WG (512 thr, 1 block/CU via launch_bounds(512,1) ->
// 256 VGPR cap). Thread j owns gate cols j, j+512. Pairs [0,96) in VGPRs
// (192 regs), [96,128) in LDS (stride 34 u32 -> 2-way alias, free).
// ---------------------------------------------------------------------------
constexpr int PV = 96;
constexpr int PL = 32;
constexpr int LSTR = 34;

DEVI float dot2acc(u32 wu, u32 hu, float acc){
#if __has_builtin(__builtin_amdgcn_fdot2)
  return __builtin_amdgcn_fdot2(__builtin_bit_cast(f16x2, wu),
                                __builtin_bit_cast(f16x2, hu), acc, false);
#else
  f16x2 a = __builtin_bit_cast(f16x2, wu), b = __builtin_bit_cast(f16x2, hu);
  return acc + (float)a.x*(float)b.x + (float)a.y*(float)b.y;
#endif
}

__global__ __launch_bounds__(512, 1) void k_lstm(const u32* __restrict__ whh,
    const f16* __restrict__ U, float* __restrict__ hTout)
{
  int b = blockIdx.x, j = threadIdx.x;
  int j2 = j + 512;

  __shared__ u32 wl[1024*LSTR];               // 136 KB
  __shared__ __align__(16) u16 hp16[256];
  __shared__ float gbuf[1024];

  u32 w0[PV], w1[PV];
  #pragma unroll
  for (int i=0; i<PV; ++i) w0[i] = whh[(size_t)i*1024 + j];
  #pragma unroll
  for (int i=0; i<PV; ++i) w1[i] = whh[(size_t)i*1024 + j2];
  #pragma unroll
  for (int p=0; p<PL; ++p){
    wl[j*LSTR + p]  = whh[(size_t)(PV+p)*1024 + j];
    wl[j2*LSTR + p] = whh[(size_t)(PV+p)*1024 + j2];
  }
  if (j < 256) hp16[j] = 0;

  float cst = 0.f, hst = 0.f;
  const f16* Ub = U + (size_t)b*T*1024;
  float u0n = (float)Ub[j];
  float u1n = (float)Ub[j2];
  __syncthreads();

  const u32* hp = (const u32*)hp16;
  for (int t=0; t<T; ++t){
    float a0a = u0n, a1a = u1n, a0b = 0.f, a1b = 0.f;
    if (t+1 < T){
      u0n = (float)Ub[(size_t)(t+1)*1024 + j];
      u1n = (float)Ub[(size_t)(t+1)*1024 + j2];
    }
    #pragma unroll
    for (int i=0; i<PV; i+=8){
      uint4 q0 = *(const uint4*)(hp + i);
      uint4 q1 = *(const uint4*)(hp + i + 4);
      a0a = dot2acc(w0[i+0], q0.x, a0a); a0a = dot2acc(w0[i+1], q0.y, a0a);
      a0a = dot2acc(w0[i+2], q0.z, a0a); a0a = dot2acc(w0[i+3], q0.w, a0a);
      a1a = dot2acc(w1[i+0], q0.x, a1a); a1a = dot2acc(w1[i+1], q0.y, a1a);
      a1a = dot2acc(w1[i+2], q0.z, a1a); a1a = dot2acc(w1[i+3], q0.w, a1a);
      a0b = dot2acc(w0[i+4], q1.x, a0b); a0b = dot2acc(w0[i+5], q1.y, a0b);
      a0b = dot2acc(w0[i+6], q1.z, a0b); a0b = dot2acc(w0[i+7], q1.w, a0b);
      a1b = dot2acc(w1[i+4], q1.x, a1b); a1b = dot2acc(w1[i+5], q1.y, a1b);
      a1b = dot2acc(w1[i+6], q1.z, a1b); a1b = dot2acc(w1[i+7], q1.w, a1b);
    }
    const u32* wp0 = wl + j*LSTR;
    const u32* wp1 = wl + j2*LSTR;
    #pragma unroll
    for (int p=0; p<PL; p+=2){
      uint2 hq = *(const uint2*)(hp + PV + p);
      uint2 wa = *(const uint2*)(wp0 + p);
      uint2 wb = *(const uint2*)(wp1 + p);
      a0a = dot2acc(wa.x, hq.x, a0a); a0b = dot2acc(wa.y, hq.y, a0b);
      a1a = dot2acc(wb.x, hq.x, a1a); a1b = dot2acc(wb.y, hq.y, a1b);
    }
    gbuf[j]  = a0a + a0b;
    gbuf[j2] = a1a + a1b;
    __syncthreads();
    if (j < 256){
      float gi = gbuf[j];
      float gf = gbuf[256 + j];
      float gg = gbuf[512 + j];
      float go = gbuf[768 + j];
      cst = fsig(gf)*cst + fsig(gi)*ftanh(gg);
      hst = fsig(go)*ftanh(cst);
      hp16[j] = __builtin_bit_cast(u16, (f16)hst);
    }
    __syncthreads();
  }
  if (j < 256) hTout[b*256 + j] = hst;
}

__global__ __launch_bounds__(256) void k_head(const float* __restrict__ hT,
    const float* __restrict__ Wc, const float* __restrict__ bc,
    float* __restrict__ out)
{
  int b = blockIdx.x, j = threadIdx.x;
  __shared__ float hs[256];
  hs[j] = hT[b*256 + j];
  __syncthreads();
  if (j < NC){
    float a = bc[j];
    for (int k=0; k<256; ++k) a += hs[k]*Wc[k*NC + j];
    out[b*NC + j] = a;
  }
}

// ---------------------------------------------------------------------------
extern "C" void kernel_launch(void* const* d_in, const int* in_sizes, int n_in,
                              void* d_out, int out_size, void* d_ws, size_t ws_size,
                              hipStream_t stream)
{
  if (ws_size < WS_TOTAL) return;

  const float* x    = (const float*)d_in[0];
  const float* eW1  = (const float*)d_in[1];
  const float* eg1  = (const float*)d_in[2];
  const float* eb1  = (const float*)d_in[3];
  const float* eW2  = (const float*)d_in[4];
  const float* eg2  = (const float*)d_in[5];
  const float* eb2  = (const float*)d_in[6];
  const float* eW3  = (const float*)d_in[7];
  const float* eg3  = (const float*)d_in[8];
  const float* eb3  = (const float*)d_in[9];
  const float* sW1  = (const float*)d_in[10];
  const float* sg1  = (const float*)d_in[11];
  const float* sb1  = (const float*)d_in[12];
  const float* sW2  = (const float*)d_in[13];
  const float* sg2  = (const float*)d_in[14];
  const float* sb2  = (const float*)d_in[15];
  const float* sW3  = (const float*)d_in[16];
  const float* sg3  = (const float*)d_in[17];
  const float* sb3  = (const float*)d_in[18];
  const float* rW   = (const float*)d_in[19];
  const float* rg   = (const float*)d_in[20];
  const float* rb   = (const float*)d_in[21];
  const float* rm1W = (const float*)d_in[22];
  const float* rm1b = (const float*)d_in[23];
  const float* rlng = (const float*)d_in[24];
  const float* rlnb = (const float*)d_in[25];
  const float* rm2W = (const float*)d_in[26];
  const float* rm2b = (const float*)d_in[27];
  const float* gW   = (const float*)d_in[28];
  const float* gb   = (const float*)d_in[29];
  const float* Wih  = (const float*)d_in[30];
  const float* Whh  = (const float*)d_in[31];
  const float* blst = (const float*)d_in[32];
  const float* Wc   = (const float*)d_in[33];
  const float* bc   = (const float*)d_in[34];

  char* ws = (char*)d_ws;
  f16*  ws1   = (f16*)(ws + OFF_WS1);
  f16*  ws2   = (f16*)(ws + OFF_WS2);
  f16*  ws3   = (f16*)(ws + OFF_WS3);
  f16*  we1   = (f16*)(ws + OFF_WE1);
  f16*  we2   = (f16*)(ws + OFF_WE2);
  f16*  we3   = (f16*)(ws + OFF_WE3);
  f16*  wr    = (f16*)(ws + OFF_WR);
  f16*  wih   = (f16*)(ws + OFF_WIH);
  u32*  whh   = (u32*)(ws + OFF_WHH);
  f16*  act0  = (f16*)(ws + OFF_ACT0);
  f16*  a1    = (f16*)(ws + OFF_A1);
  f16*  a2    = (f16*)(ws + OFF_A2);
  f16*  ract  = (f16*)(ws + OFF_RACT);
  f16*  convb = (f16*)(ws + OFF_CONV);
  float* hmix  = (float*)(ws + OFF_HMIX);
  f16*  amix  = (f16*)(ws + OFF_AMIX);
  f16*  Ubuf  = (f16*)(ws + OFF_U);
  float* stats = (float*)(ws + OFF_STAT);
  float* rh    = (float*)(ws + OFF_RH);
  float* wsel  = (float*)(ws + OFF_WSEL);
  float* hTb   = (float*)(ws + OFF_HT);

  // ---- prep ----
  k_prep_w<<<(2349056 + 255)/256, 256, 0, stream>>>(eW1,eW2,eW3,sW1,sW2,sW3,rW,Wih,Whh,ws);
  k_prep_x<<<(B*T*32 + 255)/256, 256, 0, stream>>>(x, ws);

  // ---- router ----
  k_conv<32,5><<<dim3(512,2), 256, 0, stream>>>(act0, wr, convb, nullptr, nullptr, 0, 128);
  k_gnstats<16><<<B*8, 256, 0, stream>>>(convb, stats, nullptr, 0);
  k_gnapply<16,0><<<(B*T*128)/2048, 256, 0, stream>>>(convb, stats, rg, rb, ract, nullptr, 0);
  k_gap<<<B, 512, 0, stream>>>(ract, rh);
  k_router<<<B, 128, 0, stream>>>(rh, rm1W, rm1b, rlng, rlnb, rm2W, rm2b, gW, gb, wsel);

  // ---- shared expert ----
  k_conv<32,5><<<dim3(512,1), 256, 0, stream>>>(act0, ws1, convb, nullptr, nullptr, 0, 64);
  k_gnstats<8><<<B*8, 256, 0, stream>>>(convb, stats, nullptr, 0);
  k_gnapply<8,0><<<(B*T*64)/2048, 256, 0, stream>>>(convb, stats, sg1, sb1, a1, nullptr, 0);
  k_conv<64,5><<<dim3(512,2), 256, 0, stream>>>(a1, ws2, convb, nullptr, nullptr, 0, 128);
  k_gnstats<16><<<B*8, 256, 0, stream>>>(convb, stats, nullptr, 0);
  k_gnapply<16,0><<<(B*T*128)/2048, 256, 0, stream>>>(convb, stats, sg2, sb2, a2, nullptr, 0);
  k_conv<128,5><<<dim3(512,4), 256, 0, stream>>>(a2, ws3, convb, nullptr, nullptr, 0, 256);
  k_gnstats<32><<<B*8, 256, 0, stream>>>(convb, stats, nullptr, 0);
  k_gnapply<32,1><<<(B*T*256)/2048, 256, 0, stream>>>(convb, stats, sg3, sb3, hmix, nullptr, 0);

  // ---- experts (top-2 skip) ----
  for (int e=0; e<8; ++e){
    k_conv<32,5><<<dim3(512,1), 256, 0, stream>>>(act0, we1 + (size_t)e*10240, convb, nullptr, wsel, e, 64);
    k_gnstats<8><<<B*8, 256, 0, stream>>>(convb, stats, wsel, e);
    k_gnapply<8,0><<<(B*T*64)/2048, 256, 0, stream>>>(convb, stats, eg1 + e*64, eb1 + e*64, a1, wsel, e);
    k_conv<64,5><<<dim3(512,2), 256, 0, stream>>>(a1, we2 + (size_t)e*40960, convb, nullptr, wsel, e, 128);
    k_gnstats<16><<<B*8, 256, 0, stream>>>(convb, stats, wsel, e);
    k_gnapply<16,0><<<(B*T*128)/2048, 256, 0, stream>>>(convb, stats, eg2 + e*128, eb2 + e*128, a2, wsel, e);
    k_conv<128,5><<<dim3(512,4), 256, 0, stream>>>(a2, we3 + (size_t)e*163840, convb, nullptr, wsel, e, 256);
    k_gnstats<32><<<B*8, 256, 0, stream>>>(convb, stats, wsel, e);
    k_gnapply<32,2><<<(B*T*256)/2048, 256, 0, stream>>>(convb, stats, eg3 + e*256, eb3 + e*256, hmix, wsel, e);
  }

  // ---- LSTM ----
  k_h2f16<<<(B*T*256/4 + 255)/256, 256, 0, stream>>>(hmix, amix, B*T*256/4);
  k_conv<256,1><<<dim3(512,16), 256, 0, stream>>>(amix, wih, Ubuf, blst, nullptr, 0, 1024);
  k_lstm<<<B, 512, 0, stream>>>(whh, Ubuf, hTb);
  k_head<<<B, 256, 0, stream>>>(hTb, Wc, bc, (float*)d_out);
}